// Round 1
// baseline (354.638 us; speedup 1.0000x reference)
//
#include <hip/hip_runtime.h>
#include <hip/hip_bf16.h>
#include <math.h>

// Problem constants (B=4, T=2048, D=1024, H=64), fp32 in/out.
#define Bb   4
#define Tlen 2048
#define Dd   1024
#define Hh   64

// ---------------- Kernel 1: QKV projection ----------------
// q,k,v [B*T, 64] = x [B*T, 1024] @ W [1024, 64]   (three weight matrices)
// grid: (B*T)/PROJ_ROWS blocks, 192 threads (3 waves). thread = w*64 + h,
// w in {0,1,2} selects {Wq,Wk,Wv}. x addresses are wave-uniform -> s_load.
#define PROJ_ROWS 16
__global__ __launch_bounds__(192) void qkv_proj_kernel(
    const float* __restrict__ x,  const float* __restrict__ Wq,
    const float* __restrict__ Wk, const float* __restrict__ Wv,
    float* __restrict__ qout, float* __restrict__ kout, float* __restrict__ vout)
{
    const int w = threadIdx.x >> 6;     // 0,1,2
    const int h = threadIdx.x & 63;
    const float* __restrict__ W  = (w == 0) ? Wq : (w == 1) ? Wk : Wv;
    float* __restrict__ out      = (w == 0) ? qout : (w == 1) ? kout : vout;

    const long row0 = (long)blockIdx.x * PROJ_ROWS;
    const float* __restrict__ xp = x + row0 * Dd;

    float acc[PROJ_ROWS];
    #pragma unroll
    for (int r = 0; r < PROJ_ROWS; ++r) acc[r] = 0.f;

    for (int d = 0; d < Dd; d += 4) {
        // W column reads: coalesced across the 64 lanes of each wave.
        const float wv0 = W[(d + 0) * Hh + h];
        const float wv1 = W[(d + 1) * Hh + h];
        const float wv2 = W[(d + 2) * Hh + h];
        const float wv3 = W[(d + 3) * Hh + h];
        #pragma unroll
        for (int r = 0; r < PROJ_ROWS; ++r) {
            // wave-uniform address -> scalar load (s_load_dwordx4)
            const float4 xv = *reinterpret_cast<const float4*>(xp + (long)r * Dd + d);
            acc[r] += xv.x * wv0 + xv.y * wv1 + xv.z * wv2 + xv.w * wv3;
        }
    }
    #pragma unroll
    for (int r = 0; r < PROJ_ROWS; ++r)
        out[(row0 + r) * Hh + h] = acc[r];
}

// ---------------- Kernel 2: causal flash attention (fp32) ----------------
// grid: (T/BQ, B), block 256 threads.
// thread t: qi = t>>3 (q-row in tile), hg = t&7 (owns out cols hg*8..hg*8+7,
// and computes scores for j = hg*4..hg*4+3 of each key tile).
#define BQ 32
#define BK 32
#define QSTR 68   // padded fp32 stride for 64-wide LDS tiles (4-way worst aliasing)
#define PSTR 36   // padded stride for the 32-wide P tile

__global__ __launch_bounds__(256) void attn_kernel(
    const float* __restrict__ q, const float* __restrict__ k,
    const float* __restrict__ v, float* __restrict__ out)
{
    __shared__ float qs[BQ * QSTR];
    __shared__ float ks[BK * QSTR];
    __shared__ float vs[BK * QSTR];
    __shared__ float ps[BQ * PSTR];

    const int b  = blockIdx.y;
    const int qt = blockIdx.x;
    const int t  = threadIdx.x;
    const int qi = t >> 3;          // 0..31
    const int hg = t & 7;           // 0..7
    const int hs = hg * 8;

    const long base = (long)b * Tlen * Hh;

    // ---- load Q tile (BQ x 64) into LDS, padded ----
    for (int i = t; i < BQ * 16; i += 256) {          // 512 float4s
        const int r = i >> 4, c4 = i & 15;
        const float4 vv = *reinterpret_cast<const float4*>(
            q + base + (long)(qt * BQ + r) * Hh + c4 * 4);
        *reinterpret_cast<float4*>(&qs[r * QSTR + c4 * 4]) = vv;
    }

    float o[8];
    #pragma unroll
    for (int i = 0; i < 8; ++i) o[i] = 0.f;
    float m = -INFINITY, l = 0.f;
    const float scale = 0.125f;     // 64^-0.5

    const int ntiles = qt + 1;      // causal: key tiles 0..qt
    for (int kt = 0; kt < ntiles; ++kt) {
        __syncthreads();            // protect ks/vs/ps (and qs on first iter)
        // ---- stage K,V tiles ----
        for (int i = t; i < BK * 16; i += 256) {
            const int r = i >> 4, c4 = i & 15;
            const long g = base + (long)(kt * BK + r) * Hh + c4 * 4;
            *reinterpret_cast<float4*>(&ks[r * QSTR + c4 * 4]) =
                *reinterpret_cast<const float4*>(k + g);
            *reinterpret_cast<float4*>(&vs[r * QSTR + c4 * 4]) =
                *reinterpret_cast<const float4*>(v + g);
        }
        __syncthreads();

        // ---- S = scale * Q K^T for j = hg*4..hg*4+3, causal mask ----
        float s[4];
        const int gq = qt * BQ + qi;
        #pragma unroll
        for (int jj = 0; jj < 4; ++jj) {
            const int j = hg * 4 + jj;
            float acc = 0.f;
            #pragma unroll
            for (int c4 = 0; c4 < 16; ++c4) {
                const float4 qv = *reinterpret_cast<const float4*>(&qs[qi * QSTR + c4 * 4]);
                const float4 kv = *reinterpret_cast<const float4*>(&ks[j  * QSTR + c4 * 4]);
                acc += qv.x * kv.x + qv.y * kv.y + qv.z * kv.z + qv.w * kv.w;
            }
            const int gk = kt * BK + j;
            s[jj] = (gk > gq) ? -INFINITY : acc * scale;
        }

        // ---- online softmax update (8 lanes per q-row share state) ----
        float tm = fmaxf(fmaxf(s[0], s[1]), fmaxf(s[2], s[3]));
        tm = fmaxf(tm, __shfl_xor(tm, 1));
        tm = fmaxf(tm, __shfl_xor(tm, 2));
        tm = fmaxf(tm, __shfl_xor(tm, 4));
        const float mnew  = fmaxf(m, tm);
        const float alpha = __expf(m - mnew);   // first tile: exp(-inf)=0
        float p[4], psum = 0.f;
        #pragma unroll
        for (int jj = 0; jj < 4; ++jj) { p[jj] = __expf(s[jj] - mnew); psum += p[jj]; }
        psum += __shfl_xor(psum, 1);
        psum += __shfl_xor(psum, 2);
        psum += __shfl_xor(psum, 4);
        l = l * alpha + psum;
        m = mnew;
        #pragma unroll
        for (int i = 0; i < 8; ++i) o[i] *= alpha;

        *reinterpret_cast<float4*>(&ps[qi * PSTR + hg * 4]) =
            make_float4(p[0], p[1], p[2], p[3]);
        __syncthreads();

        // ---- O += P V : o[c] += sum_j ps[qi][j] * vs[j][hs+c] ----
        #pragma unroll 8
        for (int j = 0; j < BK; ++j) {
            const float pj = ps[qi * PSTR + j];           // broadcast within hg-group
            const float4 v0 = *reinterpret_cast<const float4*>(&vs[j * QSTR + hs]);
            const float4 v1 = *reinterpret_cast<const float4*>(&vs[j * QSTR + hs + 4]);
            o[0] += pj * v0.x; o[1] += pj * v0.y; o[2] += pj * v0.z; o[3] += pj * v0.w;
            o[4] += pj * v1.x; o[5] += pj * v1.y; o[6] += pj * v1.z; o[7] += pj * v1.w;
        }
    }

    const float inv = 1.f / l;
    const long orow = base + (long)(qt * BQ + qi) * Hh + hs;
    #pragma unroll
    for (int c = 0; c < 8; ++c) out[orow + c] = o[c] * inv;
}

extern "C" void kernel_launch(void* const* d_in, const int* in_sizes, int n_in,
                              void* d_out, int out_size, void* d_ws, size_t ws_size,
                              hipStream_t stream) {
    const float* x  = (const float*)d_in[0];
    const float* Wq = (const float*)d_in[1];
    const float* Wk = (const float*)d_in[2];
    const float* Wv = (const float*)d_in[3];
    float* outp = (float*)d_out;

    // workspace: q,k,v each B*T*H fp32 = 2 MiB -> 6 MiB total
    const long n_rows = (long)Bb * Tlen;          // 8192
    float* qw = (float*)d_ws;
    float* kw = qw + n_rows * Hh;
    float* vw = kw + n_rows * Hh;

    {
        dim3 grid((unsigned)(n_rows / PROJ_ROWS));   // 512
        qkv_proj_kernel<<<grid, 192, 0, stream>>>(x, Wq, Wk, Wv, qw, kw, vw);
    }
    {
        dim3 grid(Tlen / BQ, Bb);                    // 64 x 4
        attn_kernel<<<grid, 256, 0, stream>>>(qw, kw, vw, outp);
    }
}

// Round 2
// 72.706 us; speedup vs baseline: 4.8777x; 4.8777x over previous
//
#include <hip/hip_runtime.h>
#include <math.h>

// Problem constants (B=4, T=2048, D=1024, H=64), fp32 in/out.
#define Bb   4
#define Tlen 2048
#define Dd   1024
#define Hh   64
#define NROWS 8192      // B*T
#define NQ   32         // q-tiles of 64 rows per batch
#define NC   4          // key-chunks per q-tile (flash-decoding split)

typedef short bf16x8 __attribute__((ext_vector_type(8)));
typedef float f32x4  __attribute__((ext_vector_type(4)));

__device__ __forceinline__ unsigned short f2b(float f) {
    unsigned u = __float_as_uint(f);
    unsigned r = u + 0x7FFFu + ((u >> 16) & 1u);   // RNE
    return (unsigned short)(r >> 16);
}

// ---------------- Kernel 0: W -> W^T bf16 ----------------
// wt[w][h][k] bf16, w in {q,k,v}
__global__ __launch_bounds__(256) void wtrans_kernel(
    const float* __restrict__ Wq, const float* __restrict__ Wk,
    const float* __restrict__ Wv, unsigned short* __restrict__ wt)
{
    const int h = blockIdx.x;          // 0..63
    const int w = blockIdx.y;          // 0..2
    const float* W = (w == 0) ? Wq : (w == 1) ? Wk : Wv;
    unsigned short* o = wt + ((size_t)w * 64 + h) * 1024;
    for (int k = threadIdx.x; k < 1024; k += 256)
        o[k] = f2b(W[(size_t)k * 64 + h]);
}

// ---------------- Kernel 1: QKV projection via MFMA ----------------
// out[row][h] = sum_k x[row][k] * W[k][h];  64-row M-tile, K-step 64.
#define XSTR 72   // bf16 elements per LDS row (144 B, 16B-aligned)
__global__ __launch_bounds__(256) void proj_kernel(
    const float* __restrict__ x, const unsigned short* __restrict__ wt,
    unsigned short* __restrict__ qw, unsigned short* __restrict__ kw,
    unsigned short* __restrict__ vw)
{
    __shared__ unsigned short xs[64 * XSTR];
    __shared__ unsigned short wsx[64 * XSTR];

    const int rb   = blockIdx.x * 64;
    const int wsel = blockIdx.y;
    const unsigned short* wtp = wt + (size_t)wsel * 64 * 1024;
    unsigned short* out = (wsel == 0) ? qw : (wsel == 1) ? kw : vw;

    const int tid  = threadIdx.x;
    const int wv   = tid >> 6;      // wave 0..3
    const int lane = tid & 63;
    const int qr   = lane & 15;
    const int g    = lane >> 4;

    f32x4 acc[4] = {};

    for (int k0 = 0; k0 < Dd; k0 += 64) {
        __syncthreads();
        // stage x tile [64 rows][64 k] fp32 -> bf16, XOR-swizzled 8-elem blocks
        #pragma unroll
        for (int it = 0; it < 4; ++it) {
            const int fl = tid + it * 256;
            const int r = fl >> 4, c4 = (fl & 15) * 4;
            const float4 v = *(const float4*)(x + (size_t)(rb + r) * Dd + k0 + c4);
            const unsigned lo = f2b(v.x) | ((unsigned)f2b(v.y) << 16);
            const unsigned hi = f2b(v.z) | ((unsigned)f2b(v.w) << 16);
            const int blk = c4 >> 3, sub = c4 & 7;
            *(uint2*)(&xs[r * XSTR + ((blk ^ (r & 3)) << 3) + sub]) = make_uint2(lo, hi);
        }
        // stage W^T tile [64 h][64 k] bf16 (already transposed in global)
        #pragma unroll
        for (int it = 0; it < 2; ++it) {
            const int cl = tid + it * 256;
            const int h = cl >> 3, cg = cl & 7;
            const bf16x8 w8 = *(const bf16x8*)(wtp + (size_t)h * 1024 + k0 + cg * 8);
            *(bf16x8*)(&wsx[h * XSTR + ((cg ^ (h & 3)) << 3)]) = w8;
        }
        __syncthreads();
        #pragma unroll
        for (int ks = 0; ks < 2; ++ks) {
            const int arow = wv * 16 + qr;
            const bf16x8 a = *(const bf16x8*)(&xs[arow * XSTR + ks * 32 + ((g ^ (arow & 3)) << 3)]);
            #pragma unroll
            for (int nf = 0; nf < 4; ++nf) {
                const int brow = nf * 16 + qr;
                const bf16x8 bf = *(const bf16x8*)(&wsx[brow * XSTR + ks * 32 + ((g ^ (brow & 3)) << 3)]);
                acc[nf] = __builtin_amdgcn_mfma_f32_16x16x32_bf16(a, bf, acc[nf], 0, 0, 0);
            }
        }
    }
    // D layout: col = lane&15, row = 4*(lane>>4)+r
    #pragma unroll
    for (int nf = 0; nf < 4; ++nf) {
        #pragma unroll
        for (int r = 0; r < 4; ++r) {
            const int row = rb + wv * 16 + 4 * g + r;
            const int col = nf * 16 + qr;
            out[(size_t)row * Hh + col] = f2b(acc[nf][r]);
        }
    }
}

// ---------------- Kernel 2: flash attention partials (MFMA bf16) ----------------
// grid (NQ, NC, B). Block: 4 waves; wave w owns q-rows qt*64+16w .. +15.
// Swapped QK^T: mfma(A=K, B=Q) -> lane holds S[q=lane&15][j=4*(lane>>4)+r].
#define VSTR 40   // V^T LDS row stride (80 B)
__global__ __launch_bounds__(256) void attn_kernel(
    const unsigned short* __restrict__ qw, const unsigned short* __restrict__ kw,
    const unsigned short* __restrict__ vw,
    float* __restrict__ part_O, float* __restrict__ part_ml)
{
    __shared__ unsigned short ks_s[32 * XSTR];
    __shared__ unsigned short vt_s[64 * VSTR];

    const int qt = (NQ - 1) - blockIdx.x;   // big q-tiles dispatched first
    const int ci = blockIdx.y;
    const int b  = blockIdx.z;
    const int tid = threadIdx.x;
    const int wv = tid >> 6, lane = tid & 63;
    const int qr = lane & 15, g = lane >> 4;

    const int ntk = 2 * qt + 2;                    // causal key tiles of 32
    const int tpc = (ntk + NC - 1) / NC;
    const int t0  = ci * tpc;
    const int t1  = (ntk < t0 + tpc) ? ntk : (t0 + tpc);

    const size_t base = (size_t)b * Tlen * Hh;
    const int qrow = qt * 64 + wv * 16 + qr;       // this lane's q row (within b)

    // Q fragments (k-halves 0..31, 32..63) straight from global (bf16)
    const bf16x8 qf0 = *(const bf16x8*)(qw + base + (size_t)qrow * Hh + 8 * g);
    const bf16x8 qf1 = *(const bf16x8*)(qw + base + (size_t)qrow * Hh + 32 + 8 * g);

    f32x4 o0 = {}, o1 = {}, o2 = {}, o3 = {};
    float m = -INFINITY, l = 0.f;

    for (int kt = t0; kt < t1; ++kt) {
        const int j0 = kt * 32;
        __syncthreads();
        {   // stage K tile [32][64] (row-XOR swizzle) + V^T tile [64][32] (col-group swizzle)
            const int row = tid >> 3, cg = tid & 7;
            const bf16x8 k8 = *(const bf16x8*)(kw + base + (size_t)(j0 + row) * Hh + cg * 8);
            *(bf16x8*)(&ks_s[row * XSTR + ((cg ^ (row & 3)) << 3)]) = k8;
            const bf16x8 v8 = *(const bf16x8*)(vw + base + (size_t)(j0 + row) * Hh + cg * 8);
            #pragma unroll
            for (int u = 0; u < 8; ++u) {
                const int c = cg * 8 + u;
                const int jx = row ^ (((c >> 3) & 3) << 3);
                vt_s[c * VSTR + jx] = ((const unsigned short*)&v8)[u];
            }
        }
        __syncthreads();

        // S^T = K . Q^T  (two j-frags, K contraction over H=64 in 2 steps)
        f32x4 a0 = {}, a1 = {};
        {
            const int sw = (g ^ (qr & 3)) << 3;
            bf16x8 kf;
            kf = *(const bf16x8*)(&ks_s[qr * XSTR + sw]);
            a0 = __builtin_amdgcn_mfma_f32_16x16x32_bf16(kf, qf0, a0, 0, 0, 0);
            kf = *(const bf16x8*)(&ks_s[qr * XSTR + 32 + sw]);
            a0 = __builtin_amdgcn_mfma_f32_16x16x32_bf16(kf, qf1, a0, 0, 0, 0);
            kf = *(const bf16x8*)(&ks_s[(16 + qr) * XSTR + sw]);
            a1 = __builtin_amdgcn_mfma_f32_16x16x32_bf16(kf, qf0, a1, 0, 0, 0);
            kf = *(const bf16x8*)(&ks_s[(16 + qr) * XSTR + 32 + sw]);
            a1 = __builtin_amdgcn_mfma_f32_16x16x32_bf16(kf, qf1, a1, 0, 0, 0);
        }

        // masked scores, online softmax (lane owns row q=qr; j = jf*16 + 4g + r)
        float p[8];
        float tm = -INFINITY;
        #pragma unroll
        for (int jf = 0; jf < 2; ++jf) {
            #pragma unroll
            for (int r = 0; r < 4; ++r) {
                const int jg = j0 + jf * 16 + 4 * g + r;
                float s = ((jf == 0) ? a0[r] : a1[r]) * 0.125f;
                s = (jg > qrow) ? -INFINITY : s;
                p[jf * 4 + r] = s;
                tm = fmaxf(tm, s);
            }
        }
        tm = fmaxf(tm, __shfl_xor(tm, 16));
        tm = fmaxf(tm, __shfl_xor(tm, 32));
        const float mnew  = fmaxf(m, tm);
        const float alpha = (m == -INFINITY) ? 0.f : __expf(m - mnew);
        float psum = 0.f;
        #pragma unroll
        for (int i = 0; i < 8; ++i) {
            const float pv = (p[i] == -INFINITY) ? 0.f : __expf(p[i] - mnew);
            p[i] = pv; psum += pv;
        }
        psum += __shfl_xor(psum, 16);
        psum += __shfl_xor(psum, 32);
        l = l * alpha + psum;
        m = mnew;

        // rescale O (rows q = 4g+r need alpha of that q-row)
        const float ar0 = __shfl(alpha, 4 * g + 0);
        const float ar1 = __shfl(alpha, 4 * g + 1);
        const float ar2 = __shfl(alpha, 4 * g + 2);
        const float ar3 = __shfl(alpha, 4 * g + 3);
        o0[0] *= ar0; o0[1] *= ar1; o0[2] *= ar2; o0[3] *= ar3;
        o1[0] *= ar0; o1[1] *= ar1; o1[2] *= ar2; o1[3] *= ar3;
        o2[0] *= ar0; o2[1] *= ar1; o2[2] *= ar2; o2[3] *= ar3;
        o3[0] *= ar0; o3[1] *= ar1; o3[2] *= ar2; o3[3] *= ar3;

        // repack P (S^T layout) -> PV A-fragment (8 shuffles, in-register)
        unsigned pw[4];
        pw[0] = f2b(p[0]) | ((unsigned)f2b(p[1]) << 16);   // jf0: j=4g+0,1
        pw[1] = f2b(p[2]) | ((unsigned)f2b(p[3]) << 16);   // jf0: j=4g+2,3
        pw[2] = f2b(p[4]) | ((unsigned)f2b(p[5]) << 16);   // jf1: j=16+4g+0,1
        pw[3] = f2b(p[6]) | ((unsigned)f2b(p[7]) << 16);   // jf1: j=16+4g+2,3
        union PU { unsigned u[4]; bf16x8 v; } pu;
        #pragma unroll
        for (int w = 0; w < 4; ++w) {
            const int gp  = 2 * g + (w >> 1);          // source group of j = 8g+2w
            const int src = 16 * (gp & 3) + qr;
            const unsigned t0s = __shfl(pw[0 + (w & 1)], src);
            const unsigned t1s = __shfl(pw[2 + (w & 1)], src);
            pu.u[w] = (gp & 4) ? t1s : t0s;
        }
        const bf16x8 pa = pu.v;

        // O += P . V  (B-frag from swizzled V^T)
        {
            int cb = qr;
            bf16x8 vf = *(const bf16x8*)(&vt_s[cb * VSTR + 8 * (g ^ ((cb >> 3) & 3))]);
            o0 = __builtin_amdgcn_mfma_f32_16x16x32_bf16(pa, vf, o0, 0, 0, 0);
            cb = 16 + qr;
            vf = *(const bf16x8*)(&vt_s[cb * VSTR + 8 * (g ^ ((cb >> 3) & 3))]);
            o1 = __builtin_amdgcn_mfma_f32_16x16x32_bf16(pa, vf, o1, 0, 0, 0);
            cb = 32 + qr;
            vf = *(const bf16x8*)(&vt_s[cb * VSTR + 8 * (g ^ ((cb >> 3) & 3))]);
            o2 = __builtin_amdgcn_mfma_f32_16x16x32_bf16(pa, vf, o2, 0, 0, 0);
            cb = 48 + qr;
            vf = *(const bf16x8*)(&vt_s[cb * VSTR + 8 * (g ^ ((cb >> 3) & 3))]);
            o3 = __builtin_amdgcn_mfma_f32_16x16x32_bf16(pa, vf, o3, 0, 0, 0);
        }
    }

    // write partials (unnormalized O', m, l)
    const int blin = (b * NQ + qt) * NC + ci;
    float* po = part_O + (size_t)blin * 4096;
    #pragma unroll
    for (int nf = 0; nf < 4; ++nf) {
        const f32x4 ov = (nf == 0) ? o0 : (nf == 1) ? o1 : (nf == 2) ? o2 : o3;
        #pragma unroll
        for (int r = 0; r < 4; ++r)
            po[(size_t)(wv * 16 + 4 * g + r) * 64 + nf * 16 + qr] = ov[r];
    }
    if (g == 0) {
        part_ml[(size_t)blin * 128 + wv * 16 + qr]      = m;
        part_ml[(size_t)blin * 128 + 64 + wv * 16 + qr] = l;
    }
}

// ---------------- Kernel 3: merge partials ----------------
__global__ __launch_bounds__(256) void merge_kernel(
    const float* __restrict__ part_O, const float* __restrict__ part_ml,
    float* __restrict__ out)
{
    const int idx = blockIdx.x * 256 + threadIdx.x;   // 0 .. 524287
    const int row = idx >> 6;       // 0..8191
    const int c   = idx & 63;
    const int b   = row >> 11;
    const int t   = row & 2047;
    const int qt  = t >> 6;
    const int qq  = t & 63;
    const int bl0 = (b * NQ + qt) * NC;

    float mv[NC], lv[NC];
    float M = -INFINITY;
    #pragma unroll
    for (int i = 0; i < NC; ++i) {
        mv[i] = part_ml[(size_t)(bl0 + i) * 128 + qq];
        lv[i] = part_ml[(size_t)(bl0 + i) * 128 + 64 + qq];
        if (lv[i] > 0.f) M = fmaxf(M, mv[i]);
    }
    float num = 0.f, den = 0.f;
    #pragma unroll
    for (int i = 0; i < NC; ++i) {
        if (lv[i] > 0.f) {
            const float wgt = __expf(mv[i] - M);
            num += wgt * part_O[(size_t)(bl0 + i) * 4096 + (size_t)qq * 64 + c];
            den += wgt * lv[i];
        }
    }
    out[(size_t)row * 64 + c] = num / den;
}

extern "C" void kernel_launch(void* const* d_in, const int* in_sizes, int n_in,
                              void* d_out, int out_size, void* d_ws, size_t ws_size,
                              hipStream_t stream) {
    const float* x  = (const float*)d_in[0];
    const float* Wq = (const float*)d_in[1];
    const float* Wk = (const float*)d_in[2];
    const float* Wv = (const float*)d_in[3];
    float* outp = (float*)d_out;

    // ws layout (bytes): wt 384K | qw/kw/vw 1M each | part_O 8M | part_ml 256K
    unsigned short* wt = (unsigned short*)d_ws;         // 3*64*1024
    unsigned short* qw = wt + 3 * 64 * 1024;            // 8192*64 each
    unsigned short* kw = qw + NROWS * Hh;
    unsigned short* vw = kw + NROWS * Hh;
    float* part_O  = (float*)(vw + NROWS * Hh);         // 512 * 64 * 64
    float* part_ml = part_O + 512 * 4096;               // 512 * 128

    wtrans_kernel<<<dim3(64, 3), 256, 0, stream>>>(Wq, Wk, Wv, wt);
    proj_kernel<<<dim3(NROWS / 64, 3), 256, 0, stream>>>(x, wt, qw, kw, vw);
    attn_kernel<<<dim3(NQ, NC, Bb), 256, 0, stream>>>(qw, kw, vw, part_O, part_ml);
    merge_kernel<<<dim3((NROWS * Hh) / 256), 256, 0, stream>>>(part_O, part_ml, outp);
}

// Round 3
// 51.944 us; speedup vs baseline: 6.8274x; 1.3997x over previous
//
#include <hip/hip_runtime.h>
#include <math.h>

// Problem constants (B=4, T=2048, D=1024, H=64), fp32 in/out.
#define Bb   4
#define Tlen 2048
#define Dd   1024
#define Hh   64
#define NROWS 8192      // B*T
#define NQ   32         // q-tiles of 64 rows per batch
#define NC   4          // key-chunks per q-tile (flash-decoding split)

typedef short bf16x8 __attribute__((ext_vector_type(8)));
typedef float f32x4  __attribute__((ext_vector_type(4)));

__device__ __forceinline__ unsigned short f2b(float f) {
    unsigned u = __float_as_uint(f);
    unsigned r = u + 0x7FFFu + ((u >> 16) & 1u);   // RNE
    return (unsigned short)(r >> 16);
}

// ---------------- Kernel 0: W -> W^T bf16 ----------------
// wt[n][k] bf16, n = wsel*64 + h  (192 x 1024)
__global__ __launch_bounds__(256) void wtrans_kernel(
    const float* __restrict__ Wq, const float* __restrict__ Wk,
    const float* __restrict__ Wv, unsigned short* __restrict__ wt)
{
    const int h = blockIdx.x;          // 0..63
    const int w = blockIdx.y;          // 0..2
    const float* W = (w == 0) ? Wq : (w == 1) ? Wk : Wv;
    unsigned short* o = wt + ((size_t)w * 64 + h) * 1024;
    for (int k = threadIdx.x; k < 1024; k += 256)
        o[k] = f2b(W[(size_t)k * 64 + h]);
}

// ---------------- Kernel 1: fused QKV projection via MFMA ----------------
// One pass: out[row][n] = sum_k x[row][k] * W^T[n][k], n = 0..191.
// Grid 256 blocks (32 rows each), 256 threads. Wave wv: M-half (wv&1)*16,
// N-half (wv>>1)*96 (6 frags). Double-buffered LDS, async-stage pipeline.
__global__ __launch_bounds__(256) void proj_kernel(
    const float* __restrict__ x, const unsigned short* __restrict__ wt,
    unsigned short* __restrict__ qw, unsigned short* __restrict__ kw,
    unsigned short* __restrict__ vw)
{
    __shared__ unsigned short xs[2][32 * 64];    // bf16, 8-elem XOR swizzle
    __shared__ unsigned short ws_[2][192 * 64];

    const int rb   = blockIdx.x * 32;
    const int tid  = threadIdx.x;
    const int wv   = tid >> 6;
    const int lane = tid & 63;
    const int qr   = lane & 15;
    const int g    = lane >> 4;

    // staging coords
    const int xr  = tid >> 3, xc8 = tid & 7;              // x: row 0..31, group 0..7
    const float* xg0 = x + (size_t)(rb + xr) * Dd + xc8 * 8;

    f32x4 acc[6] = {};

    float4 px0, px1;          // x prefetch (8 fp32)
    bf16x8 pw[6];             // W prefetch

    // ---- prologue: load K-step 0 ----
    px0 = *(const float4*)(xg0 + 0);
    px1 = *(const float4*)(xg0 + 4);
    #pragma unroll
    for (int it = 0; it < 6; ++it) {
        const int c = tid + it * 256, r = c >> 3, cg = c & 7;
        pw[it] = *(const bf16x8*)(wt + (size_t)r * Dd + cg * 8);
    }

    const int mb  = (wv & 1) * 16;
    const int nbr = (wv >> 1) * 96;

    #pragma unroll
    for (int t = 0; t < 16; ++t) {
        const int cur = t & 1;
        // ---- write staged data for step t into buf[cur] ----
        {
            unsigned short p8[8];
            p8[0]=f2b(px0.x); p8[1]=f2b(px0.y); p8[2]=f2b(px0.z); p8[3]=f2b(px0.w);
            p8[4]=f2b(px1.x); p8[5]=f2b(px1.y); p8[6]=f2b(px1.z); p8[7]=f2b(px1.w);
            *(bf16x8*)(&xs[cur][xr * 64 + ((xc8 ^ (xr & 7)) << 3)]) = *(const bf16x8*)p8;
            #pragma unroll
            for (int it = 0; it < 6; ++it) {
                const int c = tid + it * 256, r = c >> 3, cg = c & 7;
                *(bf16x8*)(&ws_[cur][r * 64 + ((cg ^ (r & 7)) << 3)]) = pw[it];
            }
        }
        __syncthreads();

        // ---- issue global loads for step t+1 (hide under MFMA) ----
        if (t < 15) {
            const int k0 = (t + 1) * 64;
            px0 = *(const float4*)(xg0 + k0 + 0);
            px1 = *(const float4*)(xg0 + k0 + 4);
            #pragma unroll
            for (int it = 0; it < 6; ++it) {
                const int c = tid + it * 256, r = c >> 3, cg = c & 7;
                pw[it] = *(const bf16x8*)(wt + (size_t)r * Dd + k0 + cg * 8);
            }
        }

        // ---- compute on buf[cur] ----
        #pragma unroll
        for (int ks = 0; ks < 2; ++ks) {
            const int arow = mb + qr;
            const bf16x8 a = *(const bf16x8*)(
                &xs[cur][arow * 64 + (((ks * 4 + g) ^ (arow & 7)) << 3)]);
            #pragma unroll
            for (int nf = 0; nf < 6; ++nf) {
                const int brow = nbr + nf * 16 + qr;
                const bf16x8 b = *(const bf16x8*)(
                    &ws_[cur][brow * 64 + (((ks * 4 + g) ^ (brow & 7)) << 3)]);
                acc[nf] = __builtin_amdgcn_mfma_f32_16x16x32_bf16(a, b, acc[nf], 0, 0, 0);
            }
        }
        __syncthreads();   // all waves done reading buf[cur] before it is rewritten
    }

    // ---- epilogue: D[m=4g+r][n=qr per frag] ----
    #pragma unroll
    for (int nf = 0; nf < 6; ++nf) {
        const int n = nbr + nf * 16 + qr;
        const int wsel = n >> 6, h = n & 63;
        unsigned short* out = (wsel == 0) ? qw : (wsel == 1) ? kw : vw;
        #pragma unroll
        for (int r = 0; r < 4; ++r)
            out[(size_t)(rb + mb + 4 * g + r) * Hh + h] = f2b(acc[nf][r]);
    }
}

// ---------------- Kernel 2: flash attention partials (MFMA bf16) ----------------
// grid (NQ, NC, B). Block: 4 waves; wave w owns q-rows qt*64+16w .. +15.
// Swapped QK^T: mfma(A=K, B=Q) -> lane holds S[q=lane&15][j=4*(lane>>4)+r].
#define XSTR 72
#define VSTR 40   // V^T LDS row stride (80 B)
__global__ __launch_bounds__(256) void attn_kernel(
    const unsigned short* __restrict__ qw, const unsigned short* __restrict__ kw,
    const unsigned short* __restrict__ vw,
    float* __restrict__ part_O, float* __restrict__ part_ml)
{
    __shared__ unsigned short ks_s[32 * XSTR];
    __shared__ unsigned short vt_s[64 * VSTR];

    const int qt = (NQ - 1) - blockIdx.x;   // big q-tiles dispatched first
    const int ci = blockIdx.y;
    const int b  = blockIdx.z;
    const int tid = threadIdx.x;
    const int wv = tid >> 6, lane = tid & 63;
    const int qr = lane & 15, g = lane >> 4;

    const int ntk = 2 * qt + 2;                    // causal key tiles of 32
    const int tpc = (ntk + NC - 1) / NC;
    const int t0  = ci * tpc;
    const int t1  = (ntk < t0 + tpc) ? ntk : (t0 + tpc);

    const size_t base = (size_t)b * Tlen * Hh;
    const int qrow = qt * 64 + wv * 16 + qr;       // this lane's q row (within b)

    // Q fragments (k-halves 0..31, 32..63) straight from global (bf16)
    const bf16x8 qf0 = *(const bf16x8*)(qw + base + (size_t)qrow * Hh + 8 * g);
    const bf16x8 qf1 = *(const bf16x8*)(qw + base + (size_t)qrow * Hh + 32 + 8 * g);

    f32x4 o0 = {}, o1 = {}, o2 = {}, o3 = {};
    float m = -INFINITY, l = 0.f;

    for (int kt = t0; kt < t1; ++kt) {
        const int j0 = kt * 32;
        __syncthreads();
        {   // stage K tile [32][64] (row-XOR swizzle) + V^T tile [64][32] (col-group swizzle)
            const int row = tid >> 3, cg = tid & 7;
            const bf16x8 k8 = *(const bf16x8*)(kw + base + (size_t)(j0 + row) * Hh + cg * 8);
            *(bf16x8*)(&ks_s[row * XSTR + ((cg ^ (row & 3)) << 3)]) = k8;
            const bf16x8 v8 = *(const bf16x8*)(vw + base + (size_t)(j0 + row) * Hh + cg * 8);
            #pragma unroll
            for (int u = 0; u < 8; ++u) {
                const int c = cg * 8 + u;
                const int jx = row ^ (((c >> 3) & 3) << 3);
                vt_s[c * VSTR + jx] = ((const unsigned short*)&v8)[u];
            }
        }
        __syncthreads();

        // S^T = K . Q^T  (two j-frags, K contraction over H=64 in 2 steps)
        f32x4 a0 = {}, a1 = {};
        {
            const int sw = (g ^ (qr & 3)) << 3;
            bf16x8 kf;
            kf = *(const bf16x8*)(&ks_s[qr * XSTR + sw]);
            a0 = __builtin_amdgcn_mfma_f32_16x16x32_bf16(kf, qf0, a0, 0, 0, 0);
            kf = *(const bf16x8*)(&ks_s[qr * XSTR + 32 + sw]);
            a0 = __builtin_amdgcn_mfma_f32_16x16x32_bf16(kf, qf1, a0, 0, 0, 0);
            kf = *(const bf16x8*)(&ks_s[(16 + qr) * XSTR + sw]);
            a1 = __builtin_amdgcn_mfma_f32_16x16x32_bf16(kf, qf0, a1, 0, 0, 0);
            kf = *(const bf16x8*)(&ks_s[(16 + qr) * XSTR + 32 + sw]);
            a1 = __builtin_amdgcn_mfma_f32_16x16x32_bf16(kf, qf1, a1, 0, 0, 0);
        }

        // masked scores, online softmax (lane owns row q=qr; j = jf*16 + 4g + r)
        float p[8];
        float tm = -INFINITY;
        #pragma unroll
        for (int jf = 0; jf < 2; ++jf) {
            #pragma unroll
            for (int r = 0; r < 4; ++r) {
                const int jg = j0 + jf * 16 + 4 * g + r;
                float s = ((jf == 0) ? a0[r] : a1[r]) * 0.125f;
                s = (jg > qrow) ? -INFINITY : s;
                p[jf * 4 + r] = s;
                tm = fmaxf(tm, s);
            }
        }
        tm = fmaxf(tm, __shfl_xor(tm, 16));
        tm = fmaxf(tm, __shfl_xor(tm, 32));
        const float mnew  = fmaxf(m, tm);
        const float alpha = (m == -INFINITY) ? 0.f : __expf(m - mnew);
        float psum = 0.f;
        #pragma unroll
        for (int i = 0; i < 8; ++i) {
            const float pv = (p[i] == -INFINITY) ? 0.f : __expf(p[i] - mnew);
            p[i] = pv; psum += pv;
        }
        psum += __shfl_xor(psum, 16);
        psum += __shfl_xor(psum, 32);
        l = l * alpha + psum;
        m = mnew;

        // rescale O (rows q = 4g+r need alpha of that q-row)
        const float ar0 = __shfl(alpha, 4 * g + 0);
        const float ar1 = __shfl(alpha, 4 * g + 1);
        const float ar2 = __shfl(alpha, 4 * g + 2);
        const float ar3 = __shfl(alpha, 4 * g + 3);
        o0[0] *= ar0; o0[1] *= ar1; o0[2] *= ar2; o0[3] *= ar3;
        o1[0] *= ar0; o1[1] *= ar1; o1[2] *= ar2; o1[3] *= ar3;
        o2[0] *= ar0; o2[1] *= ar1; o2[2] *= ar2; o2[3] *= ar3;
        o3[0] *= ar0; o3[1] *= ar1; o3[2] *= ar2; o3[3] *= ar3;

        // repack P (S^T layout) -> PV A-fragment (8 shuffles, in-register)
        unsigned pw[4];
        pw[0] = f2b(p[0]) | ((unsigned)f2b(p[1]) << 16);   // jf0: j=4g+0,1
        pw[1] = f2b(p[2]) | ((unsigned)f2b(p[3]) << 16);   // jf0: j=4g+2,3
        pw[2] = f2b(p[4]) | ((unsigned)f2b(p[5]) << 16);   // jf1: j=16+4g+0,1
        pw[3] = f2b(p[6]) | ((unsigned)f2b(p[7]) << 16);   // jf1: j=16+4g+2,3
        union PU { unsigned u[4]; bf16x8 v; } pu;
        #pragma unroll
        for (int w = 0; w < 4; ++w) {
            const int gp  = 2 * g + (w >> 1);          // source group of j = 8g+2w
            const int src = 16 * (gp & 3) + qr;
            const unsigned t0s = __shfl(pw[0 + (w & 1)], src);
            const unsigned t1s = __shfl(pw[2 + (w & 1)], src);
            pu.u[w] = (gp & 4) ? t1s : t0s;
        }
        const bf16x8 pa = pu.v;

        // O += P . V  (B-frag from swizzled V^T)
        {
            int cb = qr;
            bf16x8 vf = *(const bf16x8*)(&vt_s[cb * VSTR + 8 * (g ^ ((cb >> 3) & 3))]);
            o0 = __builtin_amdgcn_mfma_f32_16x16x32_bf16(pa, vf, o0, 0, 0, 0);
            cb = 16 + qr;
            vf = *(const bf16x8*)(&vt_s[cb * VSTR + 8 * (g ^ ((cb >> 3) & 3))]);
            o1 = __builtin_amdgcn_mfma_f32_16x16x32_bf16(pa, vf, o1, 0, 0, 0);
            cb = 32 + qr;
            vf = *(const bf16x8*)(&vt_s[cb * VSTR + 8 * (g ^ ((cb >> 3) & 3))]);
            o2 = __builtin_amdgcn_mfma_f32_16x16x32_bf16(pa, vf, o2, 0, 0, 0);
            cb = 48 + qr;
            vf = *(const bf16x8*)(&vt_s[cb * VSTR + 8 * (g ^ ((cb >> 3) & 3))]);
            o3 = __builtin_amdgcn_mfma_f32_16x16x32_bf16(pa, vf, o3, 0, 0, 0);
        }
    }

    // write partials (unnormalized O', m, l)
    const int blin = (b * NQ + qt) * NC + ci;
    float* po = part_O + (size_t)blin * 4096;
    #pragma unroll
    for (int nf = 0; nf < 4; ++nf) {
        const f32x4 ov = (nf == 0) ? o0 : (nf == 1) ? o1 : (nf == 2) ? o2 : o3;
        #pragma unroll
        for (int r = 0; r < 4; ++r)
            po[(size_t)(wv * 16 + 4 * g + r) * 64 + nf * 16 + qr] = ov[r];
    }
    if (g == 0) {
        part_ml[(size_t)blin * 128 + wv * 16 + qr]      = m;
        part_ml[(size_t)blin * 128 + 64 + wv * 16 + qr] = l;
    }
}

// ---------------- Kernel 3: merge partials ----------------
__global__ __launch_bounds__(256) void merge_kernel(
    const float* __restrict__ part_O, const float* __restrict__ part_ml,
    float* __restrict__ out)
{
    const int idx = blockIdx.x * 256 + threadIdx.x;   // 0 .. 524287
    const int row = idx >> 6;       // 0..8191
    const int c   = idx & 63;
    const int b   = row >> 11;
    const int t   = row & 2047;
    const int qt  = t >> 6;
    const int qq  = t & 63;
    const int bl0 = (b * NQ + qt) * NC;

    float mv[NC], lv[NC];
    float M = -INFINITY;
    #pragma unroll
    for (int i = 0; i < NC; ++i) {
        mv[i] = part_ml[(size_t)(bl0 + i) * 128 + qq];
        lv[i] = part_ml[(size_t)(bl0 + i) * 128 + 64 + qq];
        if (lv[i] > 0.f) M = fmaxf(M, mv[i]);
    }
    float num = 0.f, den = 0.f;
    #pragma unroll
    for (int i = 0; i < NC; ++i) {
        if (lv[i] > 0.f) {
            const float wgt = __expf(mv[i] - M);
            num += wgt * part_O[(size_t)(bl0 + i) * 4096 + (size_t)qq * 64 + c];
            den += wgt * lv[i];
        }
    }
    out[(size_t)row * 64 + c] = num / den;
}

extern "C" void kernel_launch(void* const* d_in, const int* in_sizes, int n_in,
                              void* d_out, int out_size, void* d_ws, size_t ws_size,
                              hipStream_t stream) {
    const float* x  = (const float*)d_in[0];
    const float* Wq = (const float*)d_in[1];
    const float* Wk = (const float*)d_in[2];
    const float* Wv = (const float*)d_in[3];
    float* outp = (float*)d_out;

    // ws layout: wt 384K | qw/kw/vw 1M each | part_O 8M | part_ml 256K
    unsigned short* wt = (unsigned short*)d_ws;         // 192*1024
    unsigned short* qw = wt + 192 * 1024;               // 8192*64 each
    unsigned short* kw = qw + NROWS * Hh;
    unsigned short* vw = kw + NROWS * Hh;
    float* part_O  = (float*)(vw + NROWS * Hh);         // 512 * 64 * 64
    float* part_ml = part_O + 512 * 4096;               // 512 * 128

    wtrans_kernel<<<dim3(64, 3), 256, 0, stream>>>(Wq, Wk, Wv, wt);
    proj_kernel<<<dim3(NROWS / 32), 256, 0, stream>>>(x, wt, qw, kw, vw);
    attn_kernel<<<dim3(NQ, NC, Bb), 256, 0, stream>>>(qw, kw, vw, part_O, part_ml);
    merge_kernel<<<dim3((NROWS * Hh) / 256), 256, 0, stream>>>(part_O, part_ml, outp);
}